// Round 20
// baseline (201.033 us; speedup 1.0000x reference)
//
#include <hip/hip_runtime.h>
#include <stdint.h>

typedef short bf16x8 __attribute__((ext_vector_type(8)));
typedef unsigned short us8 __attribute__((ext_vector_type(8)));
typedef float f32x4 __attribute__((ext_vector_type(4)));
typedef unsigned short u16;
typedef unsigned int u32;

__device__ __forceinline__ u16 f2bf(float f) {
    u32 u = __float_as_uint(f);
    return (u16)((u + 0x7FFFu + ((u >> 16) & 1u)) >> 16);   // RNE
}

__device__ __forceinline__ u32 cvtpk(float lo, float hi) {   // D.lo=bf16(lo), D.hi=bf16(hi)
    u32 r;
    asm("v_cvt_pk_bf16_f32 %0, %1, %2" : "=v"(r) : "v"(lo), "v"(hi));
    return r;
}

typedef __attribute__((address_space(3))) unsigned int lds_uint;
typedef const __attribute__((address_space(1))) unsigned int glb_uint;
__device__ __forceinline__ void gld16(const void* g, void* l) {
    __builtin_amdgcn_global_load_lds((glb_uint*)g, (lds_uint*)l, 16, 0, 0);
}

#define VWAIT(n) asm volatile("s_waitcnt vmcnt(" #n ") lgkmcnt(0)" ::: "memory")
#define LWAIT    asm volatile("s_waitcnt lgkmcnt(0)" ::: "memory")
#define BARRIER  do { __builtin_amdgcn_s_barrier(); __builtin_amdgcn_sched_barrier(0); } while (0)

// ---- swizzled staging (rule #21), 8-wave/512-thread variants (R12-verified) ----

// [64 rows][128 cols] bf16 tile; slot = g ^ (row&7)  (2 gld16/thread)
__device__ __forceinline__ void gld8_t64x128(const u16* __restrict__ g, int64_t stride,
                                             u16* lds, int w, int lane) {
#pragma unroll
    for (int i = 0; i < 2; ++i) {
        const int gg = w * 2 + i;                     // 0..15 -> rows gg*4..+3
        const int row = gg * 4 + (lane >> 4);
        const int gs = (lane & 15) ^ (row & 7);
        gld16(g + (int64_t)row * stride + (gs << 3), &lds[gg * 512]);
    }
}
__device__ __forceinline__ int idxT(int row, int gk) {    // [*][128] read
    return row * 128 + ((gk ^ (row & 7)) << 3);
}

// [128 rows][64 cols] bf16 tile (V^T chunk); slot = g3 ^ (row&7)  (2 gld16/thread)
__device__ __forceinline__ void gld8_v128x64(const u16* __restrict__ g, int64_t stride,
                                             u16* lds, int w, int lane) {
#pragma unroll
    for (int i = 0; i < 2; ++i) {
        const int seg = w * 2 + i;                    // 0..15 -> rows seg*8..+7
        const int row = seg * 8 + (lane >> 3);
        const int gs = (lane & 7) ^ (row & 7);
        gld16(g + (int64_t)row * stride + (gs << 3), &lds[seg * 512]);
    }
}
__device__ __forceinline__ int idxV(int row, int g3) {    // [128][64] read
    return row * 64 + ((g3 ^ (row & 7)) << 3);
}

// ---------------- K0: all four f32->bf16 conversions in one launch
__global__ void k0_all(const float* __restrict__ wqkv, const float* __restrict__ x,
                       const float* __restrict__ ctx, const float* __restrict__ wproj,
                       u16* __restrict__ Wh, u16* __restrict__ Xh,
                       u16* __restrict__ Phw) {
    const int gid = blockIdx.x;
    const float* src; u16* dst; int mode; int lg;
    if (gid < 1536)      { src = wqkv;  dst = Wh;  mode = 0; lg = gid; }
    else if (gid < 3584) { src = x;     dst = Xh;  mode = 1; lg = gid - 1536; }
    else if (gid < 5632) { src = ctx;   dst = Xh;  mode = 2; lg = gid - 3584; }
    else                 { src = wproj; dst = Phw; mode = 0; lg = gid - 5632; }
    const int64_t base = ((int64_t)lg * 256 + threadIdx.x) * 8;
    const int row = (int)(base >> 10), col = (int)(base & 1023);
    int orow = row;
    if (mode == 1) orow = row + ((row >> 10) << 10);
    else if (mode == 2) orow = row + (((row >> 10) + 1) << 10);
    const float4* sp = reinterpret_cast<const float4*>(src + base);
    float4 a = sp[0], b = sp[1];
    float v[8] = {a.x, a.y, a.z, a.w, b.x, b.y, b.z, b.w};
    us8 hh;
#pragma unroll
    for (int j = 0; j < 8; ++j) hh[j] = f2bf(v[j]);
    *reinterpret_cast<us8*>(&dst[(int64_t)orow * 1024 + col]) = hh;
}

// ---------------- 8-phase GEMM template (R17/R19 proven), BM=256 x BN=128 x BK=64
// T1 XCD swizzle: each XCD owns 4 contiguous m-rows x all n.
template<bool ISK4, int NBX>
__global__ __launch_bounds__(512, 1) void gemm8p(const u16* __restrict__ Ap,
                                                 const u16* __restrict__ Bp,
                                                 const float* __restrict__ bias,
                                                 u16* __restrict__ outh,
                                                 float* __restrict__ outf) {
    __shared__ u16 L[3][2][8192];                  // 96 KB
    const int tid = threadIdx.x, lane = tid & 63;
    const int w = tid >> 6, wm = w >> 2, wn = w & 3;
    const int rl = lane & 15, gk = lane >> 4, r4 = gk << 2;
    const u32 wgid = blockIdx.x;
    const int xcd = wgid & 7, t6 = wgid >> 3;
    const int by = xcd * 4 + t6 / NBX, bx = t6 % NBX;
    const int n0 = bx << 7, m0 = by << 8;
    const u16* Ab = Ap + (int64_t)m0 * 1024;
    const u16* Bb = Bp + (int64_t)n0 * 1024;
    const int srow0 = tid >> 3, scol = tid & 7;
    f32x4 acc[2][4][2] = {};
    bf16x8 afr[4][2];

#define STAGE1(X, KT) do { if ((X) >= 0 && (KT) < 16) {                          \
    const u16* _b = (((X) < 2) ? (Ab + (int64_t)((X) * 128) * 1024) : Bb)        \
                    + (KT) * 64;                                                 \
    u16* _l = &L[((X) < 0) ? 0 : (X)][(KT) & 1][0];                              \
    _Pragma("unroll") for (int _j = 0; _j < 2; ++_j) {                           \
        const int _r = _j * 64 + srow0;                                          \
        const int _g = scol ^ (_r & 7);                                          \
        gld16(_b + (int64_t)_r * 1024 + _g * 8, &_l[_r * 64 + scol * 8]);        \
    } } } while (0)

#define RDF(X, PAR, ROW, KHGK)                                                   \
    (*reinterpret_cast<const bf16x8*>(                                           \
        &L[(X)][(PAR)][(ROW) * 64 + (((KHGK) ^ ((ROW) & 7)) << 3)]))

#define PHASE(QM, QN, PAR, STX, STKT, WMODE) do {                                \
    STAGE1(STX, STKT);                                                           \
    if ((WMODE) == 1) { VWAIT(4); } else if ((WMODE) == 2) { VWAIT(0); }         \
    __builtin_amdgcn_s_barrier(); __builtin_amdgcn_sched_barrier(0);             \
    if ((QN) == 0) {                                                             \
        _Pragma("unroll") for (int _mf = 0; _mf < 4; ++_mf) {                    \
            afr[_mf][0] = RDF(QM, PAR, wm * 64 + _mf * 16 + rl, gk);             \
            afr[_mf][1] = RDF(QM, PAR, wm * 64 + _mf * 16 + rl, 4 + gk);         \
        } }                                                                      \
    bf16x8 _b0 = RDF(2, PAR, (QN) * 64 + wn * 16 + rl, gk);                      \
    bf16x8 _b1 = RDF(2, PAR, (QN) * 64 + wn * 16 + rl, 4 + gk);                  \
    LWAIT; __builtin_amdgcn_sched_barrier(0);                                    \
    __builtin_amdgcn_s_setprio(1);                                               \
    _Pragma("unroll") for (int _mf = 0; _mf < 4; ++_mf) {                        \
        acc[QM][_mf][QN] = __builtin_amdgcn_mfma_f32_16x16x32_bf16(              \
            afr[_mf][0], _b0, acc[QM][_mf][QN], 0, 0, 0);                        \
        acc[QM][_mf][QN] = __builtin_amdgcn_mfma_f32_16x16x32_bf16(              \
            afr[_mf][1], _b1, acc[QM][_mf][QN], 0, 0, 0);                        \
    }                                                                            \
    __builtin_amdgcn_s_setprio(0);                                               \
    __builtin_amdgcn_s_barrier(); __builtin_amdgcn_sched_barrier(0);             \
} while (0)

    STAGE1(0, 0); STAGE1(1, 0); STAGE1(2, 0); STAGE1(0, 1);
    for (int i = 0; i < 8; ++i) {
        const int t = 2 * i;
        PHASE(0, 0, 0, 1, t + 1, 1);
        PHASE(0, 1, 0, 2, t + 1, 0);
        PHASE(1, 0, 0, 0, t + 2, 0);
        PHASE(1, 1, 0, -1, 0, 0);
        PHASE(0, 0, 1, 1, t + 2, (i == 7) ? 2 : 1);
        PHASE(0, 1, 1, 2, t + 2, 0);
        PHASE(1, 0, 1, 0, t + 3, 0);
        PHASE(1, 1, 1, -1, 0, 0);
    }
#undef PHASE
#undef RDF
#undef STAGE1
#pragma unroll
    for (int qm = 0; qm < 2; ++qm)
#pragma unroll
        for (int mf = 0; mf < 4; ++mf)
#pragma unroll
            for (int qn = 0; qn < 2; ++qn)
#pragma unroll
                for (int j = 0; j < 4; ++j) {
                    const int row = m0 + qm * 128 + wm * 64 + mf * 16 + r4 + j;
                    const int col = n0 + qn * 64 + wn * 16 + rl;
                    if (ISK4)
                        outf[(int64_t)row * 1024 + col] = acc[qm][mf][qn][j] + bias[col];
                    else
                        outh[(int64_t)row * 3072 + col] = f2bf(acc[qm][mf][qn][j]);
                }
}

// ---------------- K0v: pre-transpose V planes: Vt[z][e 128][kpos 1024]
__global__ __launch_bounds__(256, 2) void k0v_vt(const u16* __restrict__ Qh,
                                                 u16* __restrict__ Vt) {
    __shared__ u16 T[128][144];
    const int tid = threadIdx.x;
    const int z = blockIdx.y, b = z >> 4, h = z & 15;
    const int kt = blockIdx.x;
    const int c0v = (h < 8) ? (1024 + h * 128) : (2048 + (h - 8) * 128);
    const u16* Vbase = Qh + ((int64_t)b * 2048 + 1) * 3072 + c0v;
    const int row = tid >> 1, e0 = (tid & 1) << 6;
    const u16* src = Vbase + (int64_t)(kt * 128 + row) * 6144 + e0;
#pragma unroll
    for (int i = 0; i < 8; ++i) {
        us8 v = *reinterpret_cast<const us8*>(src + i * 8);
#pragma unroll
        for (int j = 0; j < 8; ++j) T[e0 + i * 8 + j][row] = v[j];
    }
    __syncthreads();
    const int e = tid >> 1, k0 = (tid & 1) << 6;
    u16* dst = Vt + ((int64_t)z << 17) + (int64_t)e * 1024 + kt * 128 + k0;
#pragma unroll
    for (int i = 0; i < 8; ++i)
        *reinterpret_cast<us8*>(dst + i * 8) = *reinterpret_cast<const us8*>(&T[e][k0 + i * 8]);
}

// ---------------- K23 v9: v8 + single-barrier pass 2 via double-buffered Ph.
// Ph[1] OVERLAYS LQ (dead after pass 1) — zero extra LDS, still 2 blocks/CU.
// Per pass-2 chunk t: one top barrier; write Ph[(t+1)&1] (next chunk) while PV
// reads Ph[t&1] (written last chunk; visible via top VWAIT's lgkmcnt(0) +
// barrier). WAR: readers of the write target finished one barrier ago.
// vmcnt (stores un-fenced, in-order): t=0 VWAIT(2), else VWAIT(4)
//   (newer-than-V(t) = V(t+1)[2 ops] + st(t-1)[2 ops]).
__global__ __launch_bounds__(512, 4) void k23_fused(const u16* __restrict__ Qh,
                                                    const u16* __restrict__ Vt,
                                                    float* __restrict__ attn,
                                                    u16* __restrict__ Obf) {
    __shared__ u16 LQ[8192];                         // 64x128 (pass 1) / Ph[1] (pass 2)
    __shared__ u16 LKV[3][8192];                     // 3 x (64x128 K | 128x64 V^T)
    __shared__ u16 PhA[64 * 72];                     // Ph[0]
    __shared__ float pS[8][32];
    __shared__ float rowInv[64];
    u16* const PhB = LQ;                             // Ph[1] overlay
    const int tid = threadIdx.x, lane = tid & 63, w = tid >> 6;
    const u32 wgid = blockIdx.x;
    const int xcd = wgid & 7, t0 = wgid >> 3;        // T1: same-z -> same XCD
    const int mt = t0 & 15, z = ((t0 >> 4) << 3) + xcd;
    const int b = z >> 4, h = z & 15;
    const int m0 = mt << 6;                          // 64 q-rows per block
    const int kt = w & 3, qh = w >> 2;               // QK^T roles
    const int qq = w & 3, sv = w >> 2;               // PV roles
    const int rl = lane & 15, gk = lane >> 4, r4 = gk << 2;
    const u16* Qbase = Qh + ((int64_t)b * 2048 + 2 * m0) * 3072 + h * 128;
    const int pk  = (h < 8) ? 0 : 1;
    const int c0k = (h < 8) ? (2048 + h * 128) : ((h - 8) * 128);
    const u16* Kbase = Qh + ((int64_t)b * 2048 + pk) * 3072 + c0k;
    const u16* Vtz = Vt + ((int64_t)z << 17);
    float* attnZ = attn + ((int64_t)z << 20) + (int64_t)m0 * 1024;
    gld8_t64x128(Qbase, 6144, LQ, w, lane);          // Q 64x128 (2 ops)
    gld8_t64x128(Kbase,             6144, LKV[0], w, lane);
    gld8_t64x128(Kbase + 64 * 6144, 6144, LKV[1], w, lane);
    // ---- pass 1: swapped mfma(K,Q) -> s, exp-once -> packed p~ + running sums
    u32 pk0[32], pk1[32];
    float ssum0 = 0.f, ssum1 = 0.f;
#pragma unroll
    for (int t = 0; t < 16; ++t) {
        if (t == 15) { VWAIT(0); } else { VWAIT(2); }
        BARRIER;
        if (t < 14)
            gld8_t64x128(Kbase + (int64_t)(t + 2) * 64 * 6144, 6144, LKV[(t + 2) % 3], w, lane);
        f32x4 s0 = {}, s1 = {};
#pragma unroll
        for (int ks = 0; ks < 4; ++ks) {
            bf16x8 kf = *reinterpret_cast<const bf16x8*>(&LKV[t % 3][idxT(kt * 16 + rl, ks * 4 + gk)]);
            bf16x8 q0 = *reinterpret_cast<const bf16x8*>(&LQ[idxT(qh * 32 + rl, ks * 4 + gk)]);
            bf16x8 q1 = *reinterpret_cast<const bf16x8*>(&LQ[idxT(qh * 32 + 16 + rl, ks * 4 + gk)]);
            s0 = __builtin_amdgcn_mfma_f32_16x16x32_bf16(kf, q0, s0, 0, 0, 0);
            s1 = __builtin_amdgcn_mfma_f32_16x16x32_bf16(kf, q1, s1, 0, 0, 0);
        }
        float p0[4], p1[4];
#pragma unroll
        for (int j = 0; j < 4; ++j) {
            p0[j] = __expf(s0[j] * 0.125f); ssum0 += p0[j];
            p1[j] = __expf(s1[j] * 0.125f); ssum1 += p1[j];
        }
        pk0[2 * t]     = cvtpk(p0[0], p0[1]);
        pk1[2 * t]     = cvtpk(p0[2], p0[3]);
        pk0[2 * t + 1] = cvtpk(p1[0], p1[1]);
        pk1[2 * t + 1] = cvtpk(p1[2], p1[3]);
    }
    // ---- stats: reduce over gk groups, then over the 4 kt-waves per q-half
    ssum0 += __shfl_xor(ssum0, 16); ssum0 += __shfl_xor(ssum0, 32);
    ssum1 += __shfl_xor(ssum1, 16); ssum1 += __shfl_xor(ssum1, 32);
    if (lane < 16) { pS[w][lane] = ssum0; pS[w][16 + lane] = ssum1; }
    LWAIT; BARRIER;                                  // all K/LQ readers done
    gld8_v128x64(Vtz,      1024, LKV[0], w, lane);   // V chunks 0,1 overlap stats
    gld8_v128x64(Vtz + 64, 1024, LKV[1], w, lane);
    if (tid < 64) {
        const int qb = (tid >> 5) << 2;              // q-half -> wave group base
        rowInv[tid] = 1.0f / (pS[qb][tid & 31] + pS[qb + 1][tid & 31]
                              + pS[qb + 2][tid & 31] + pS[qb + 3][tid & 31]);
    }
    LWAIT; BARRIER;
    const float Iq0 = rowInv[qh * 32 + rl], Iq1 = rowInv[qh * 32 + 16 + rl];
    float IqO[4];
#pragma unroll
    for (int j = 0; j < 4; ++j) IqO[j] = rowInv[qq * 16 + r4 + j];
    // ---- pass-2 prologue: Ph[0] (PhA) <- chunk 0's P
    *reinterpret_cast<uint2*>(&PhA[(qh * 32 + rl) * 72 + kt * 16 + r4])
        = make_uint2(pk0[0], pk1[0]);
    *reinterpret_cast<uint2*>(&PhA[(qh * 32 + 16 + rl) * 72 + kt * 16 + r4])
        = make_uint2(pk0[1], pk1[1]);
    // ---- pass 2: ONE barrier per chunk (Ph double-buffered PhA/PhB)
    f32x4 po[4] = {};
#pragma unroll
    for (int t = 0; t < 16; ++t) {
        if (t == 0) { VWAIT(2); } else { VWAIT(4); }
        BARRIER;                                     // V(t) + Ph[t&1] visible
        if (t < 14)
            gld8_v128x64(Vtz + (t + 2) * 64, 1024, LKV[(t + 2) % 3], w, lane);
        u16* const Pw = (t & 1) ? PhA : PhB;         // chunk t+1 -> parity (t+1)&1
        const u16* const Pr = (t & 1) ? PhB : PhA;   // chunk t
        if (t < 15) {                                // stage NEXT chunk's P
            *reinterpret_cast<uint2*>(&Pw[(qh * 32 + rl) * 72 + kt * 16 + r4])
                = make_uint2(pk0[2 * t + 2], pk1[2 * t + 2]);
            *reinterpret_cast<uint2*>(&Pw[(qh * 32 + 16 + rl) * 72 + kt * 16 + r4])
                = make_uint2(pk0[2 * t + 3], pk1[2 * t + 3]);
        }
        {                                            // attn stores for chunk t
            const u32 a0 = pk0[2 * t], a1 = pk1[2 * t];
            const u32 b0 = pk0[2 * t + 1], b1 = pk1[2 * t + 1];
            *reinterpret_cast<float4*>(&attnZ[(int64_t)(qh * 32 + rl) * 1024 + t * 64 + kt * 16 + r4])
                = make_float4(__uint_as_float(a0 << 16) * Iq0,
                              __uint_as_float(a0 & 0xFFFF0000u) * Iq0,
                              __uint_as_float(a1 << 16) * Iq0,
                              __uint_as_float(a1 & 0xFFFF0000u) * Iq0);
            *reinterpret_cast<float4*>(&attnZ[(int64_t)(qh * 32 + 16 + rl) * 1024 + t * 64 + kt * 16 + r4])
                = make_float4(__uint_as_float(b0 << 16) * Iq1,
                              __uint_as_float(b0 & 0xFFFF0000u) * Iq1,
                              __uint_as_float(b1 << 16) * Iq1,
                              __uint_as_float(b1 & 0xFFFF0000u) * Iq1);
        }
        // PV: A from Pr (written last chunk), B from LKV[t%3]
        bf16x8 pa0 = *reinterpret_cast<const bf16x8*>(&Pr[(qq * 16 + rl) * 72 + gk * 8]);
        bf16x8 pa1 = *reinterpret_cast<const bf16x8*>(&Pr[(qq * 16 + rl) * 72 + 32 + gk * 8]);
#pragma unroll
        for (int n = 0; n < 4; ++n) {
            bf16x8 bv0 = *reinterpret_cast<const bf16x8*>(&LKV[t % 3][idxV(sv * 64 + n * 16 + rl, gk)]);
            bf16x8 bv1 = *reinterpret_cast<const bf16x8*>(&LKV[t % 3][idxV(sv * 64 + n * 16 + rl, 4 + gk)]);
            po[n] = __builtin_amdgcn_mfma_f32_16x16x32_bf16(pa0, bv0, po[n], 0, 0, 0);
            po[n] = __builtin_amdgcn_mfma_f32_16x16x32_bf16(pa1, bv1, po[n], 0, 0, 0);
        }
    }
    // ---- epilogue: O normalize + scatter
    const int poh = h >> 3, cb2 = (h & 7) << 7;
#pragma unroll
    for (int n = 0; n < 4; ++n)
#pragma unroll
        for (int j = 0; j < 4; ++j) {
            const int qrow = m0 + qq * 16 + r4 + j;
            Obf[((int64_t)b * 2048 + 2 * qrow + poh) * 1024
                + cb2 + sv * 64 + n * 16 + rl] = f2bf(po[n][j] * IqO[j]);
        }
}

extern "C" void kernel_launch(void* const* d_in, const int* in_sizes, int n_in,
                              void* d_out, int out_size, void* d_ws, size_t ws_size,
                              hipStream_t stream) {
    const float* x     = (const float*)d_in[0];
    const float* ctx   = (const float*)d_in[1];
    const float* wqkv  = (const float*)d_in[2];
    const float* wproj = (const float*)d_in[3];
    const float* bias  = (const float*)d_in[4];
    float* out  = (float*)d_out;                 // [4,2048,1024]
    float* attn = out + 8388608;                 // [4,16,1024,1024] f32

    // ws (u16), total 92.3 MB
    u16* Qh  = (u16*)d_ws;                       // [8192,3072]
    u16* Vt  = Qh + 25165824;                    // [64,128,1024]
    u16* Wh  = Vt + 8388608;                     // [3072,1024]
    u16* Phw = Wh + 3145728;                     // [1024,1024]
    u16* Obf = Phw + 1048576;                    // [8192,1024]

    // X bf16 plane parked in the attn region (dead once k1 finishes)
    u16* Xh = (u16*)attn;                        // [8192,1024]

    k0_all            <<<dim3(6144), 256, 0, stream>>>(wqkv, x, ctx, wproj, Wh, Xh, Phw);
    gemm8p<false, 24> <<<dim3(768),  512, 0, stream>>>(Xh, Wh, nullptr, Qh, nullptr);
    k0v_vt            <<<dim3(8, 64), 256, 0, stream>>>(Qh, Vt);
    k23_fused         <<<dim3(1024), 512, 0, stream>>>(Qh, Vt, attn, Obf);
    gemm8p<true, 8>   <<<dim3(256),  512, 0, stream>>>(Obf, Phw, bias, nullptr, out);
}

// Round 21
// 199.725 us; speedup vs baseline: 1.0065x; 1.0065x over previous
//
#include <hip/hip_runtime.h>
#include <stdint.h>

typedef short bf16x8 __attribute__((ext_vector_type(8)));
typedef unsigned short us8 __attribute__((ext_vector_type(8)));
typedef float f32x4 __attribute__((ext_vector_type(4)));
typedef unsigned short u16;
typedef unsigned int u32;

__device__ __forceinline__ u16 f2bf(float f) {
    u32 u = __float_as_uint(f);
    return (u16)((u + 0x7FFFu + ((u >> 16) & 1u)) >> 16);   // RNE
}

__device__ __forceinline__ u32 cvtpk(float lo, float hi) {   // D.lo=bf16(lo), D.hi=bf16(hi)
    u32 r;
    asm("v_cvt_pk_bf16_f32 %0, %1, %2" : "=v"(r) : "v"(lo), "v"(hi));
    return r;
}

typedef __attribute__((address_space(3))) unsigned int lds_uint;
typedef const __attribute__((address_space(1))) unsigned int glb_uint;
__device__ __forceinline__ void gld16(const void* g, void* l) {
    __builtin_amdgcn_global_load_lds((glb_uint*)g, (lds_uint*)l, 16, 0, 0);
}

#define VWAIT(n) asm volatile("s_waitcnt vmcnt(" #n ") lgkmcnt(0)" ::: "memory")
#define LWAIT    asm volatile("s_waitcnt lgkmcnt(0)" ::: "memory")
#define BARRIER  do { __builtin_amdgcn_s_barrier(); __builtin_amdgcn_sched_barrier(0); } while (0)

// ---- swizzled staging (rule #21), 8-wave/512-thread variants (R12-verified) ----

// [64 rows][128 cols] bf16 tile; slot = g ^ (row&7)  (2 gld16/thread)
__device__ __forceinline__ void gld8_t64x128(const u16* __restrict__ g, int64_t stride,
                                             u16* lds, int w, int lane) {
#pragma unroll
    for (int i = 0; i < 2; ++i) {
        const int gg = w * 2 + i;                     // 0..15 -> rows gg*4..+3
        const int row = gg * 4 + (lane >> 4);
        const int gs = (lane & 15) ^ (row & 7);
        gld16(g + (int64_t)row * stride + (gs << 3), &lds[gg * 512]);
    }
}
__device__ __forceinline__ int idxT(int row, int gk) {    // [*][128] read
    return row * 128 + ((gk ^ (row & 7)) << 3);
}

// [128 rows][64 cols] bf16 tile (V^T chunk); slot = g3 ^ (row&7)  (2 gld16/thread)
__device__ __forceinline__ void gld8_v128x64(const u16* __restrict__ g, int64_t stride,
                                             u16* lds, int w, int lane) {
#pragma unroll
    for (int i = 0; i < 2; ++i) {
        const int seg = w * 2 + i;                    // 0..15 -> rows seg*8..+7
        const int row = seg * 8 + (lane >> 3);
        const int gs = (lane & 7) ^ (row & 7);
        gld16(g + (int64_t)row * stride + (gs << 3), &lds[seg * 512]);
    }
}
__device__ __forceinline__ int idxV(int row, int g3) {    // [128][64] read
    return row * 64 + ((g3 ^ (row & 7)) << 3);
}

// ---------------- K0: all four f32->bf16 conversions in one launch
__global__ void k0_all(const float* __restrict__ wqkv, const float* __restrict__ x,
                       const float* __restrict__ ctx, const float* __restrict__ wproj,
                       u16* __restrict__ Wh, u16* __restrict__ Xh,
                       u16* __restrict__ Phw) {
    const int gid = blockIdx.x;
    const float* src; u16* dst; int mode; int lg;
    if (gid < 1536)      { src = wqkv;  dst = Wh;  mode = 0; lg = gid; }
    else if (gid < 3584) { src = x;     dst = Xh;  mode = 1; lg = gid - 1536; }
    else if (gid < 5632) { src = ctx;   dst = Xh;  mode = 2; lg = gid - 3584; }
    else                 { src = wproj; dst = Phw; mode = 0; lg = gid - 5632; }
    const int64_t base = ((int64_t)lg * 256 + threadIdx.x) * 8;
    const int row = (int)(base >> 10), col = (int)(base & 1023);
    int orow = row;
    if (mode == 1) orow = row + ((row >> 10) << 10);
    else if (mode == 2) orow = row + (((row >> 10) + 1) << 10);
    const float4* sp = reinterpret_cast<const float4*>(src + base);
    float4 a = sp[0], b = sp[1];
    float v[8] = {a.x, a.y, a.z, a.w, b.x, b.y, b.z, b.w};
    us8 hh;
#pragma unroll
    for (int j = 0; j < 8; ++j) hh[j] = f2bf(v[j]);
    *reinterpret_cast<us8*>(&dst[(int64_t)orow * 1024 + col]) = hh;
}

// ---------------- 8-phase GEMM template (R17 proven), BM=256 x BN=128 x BK=64.
// 1D grid with T1 XCD swizzle: each XCD owns 4 contiguous m-rows x all n
// (its 4 A-panels = 2 MB fit the 4 MB per-XCD L2). NBX = blocks along n.
template<bool ISK4, int NBX>
__global__ __launch_bounds__(512, 1) void gemm8p(const u16* __restrict__ Ap,
                                                 const u16* __restrict__ Bp,
                                                 const float* __restrict__ bias,
                                                 u16* __restrict__ outh,
                                                 float* __restrict__ outf) {
    __shared__ u16 L[3][2][8192];                  // 96 KB
    const int tid = threadIdx.x, lane = tid & 63;
    const int w = tid >> 6, wm = w >> 2, wn = w & 3;
    const int rl = lane & 15, gk = lane >> 4, r4 = gk << 2;
    const u32 wgid = blockIdx.x;
    const int xcd = wgid & 7, t6 = wgid >> 3;      // T1: 4 m-rows per XCD chunk
    const int by = xcd * 4 + t6 / NBX, bx = t6 % NBX;
    const int n0 = bx << 7, m0 = by << 8;
    const u16* Ab = Ap + (int64_t)m0 * 1024;
    const u16* Bb = Bp + (int64_t)n0 * 1024;
    const int srow0 = tid >> 3, scol = tid & 7;
    f32x4 acc[2][4][2] = {};
    bf16x8 afr[4][2];

#define STAGE1(X, KT) do { if ((X) >= 0 && (KT) < 16) {                          \
    const u16* _b = (((X) < 2) ? (Ab + (int64_t)((X) * 128) * 1024) : Bb)        \
                    + (KT) * 64;                                                 \
    u16* _l = &L[((X) < 0) ? 0 : (X)][(KT) & 1][0];                              \
    _Pragma("unroll") for (int _j = 0; _j < 2; ++_j) {                           \
        const int _r = _j * 64 + srow0;                                          \
        const int _g = scol ^ (_r & 7);                                          \
        gld16(_b + (int64_t)_r * 1024 + _g * 8, &_l[_r * 64 + scol * 8]);        \
    } } } while (0)

#define RDF(X, PAR, ROW, KHGK)                                                   \
    (*reinterpret_cast<const bf16x8*>(                                           \
        &L[(X)][(PAR)][(ROW) * 64 + (((KHGK) ^ ((ROW) & 7)) << 3)]))

#define PHASE(QM, QN, PAR, STX, STKT, WMODE) do {                                \
    STAGE1(STX, STKT);                                                           \
    if ((WMODE) == 1) { VWAIT(4); } else if ((WMODE) == 2) { VWAIT(0); }         \
    __builtin_amdgcn_s_barrier(); __builtin_amdgcn_sched_barrier(0);             \
    if ((QN) == 0) {                                                             \
        _Pragma("unroll") for (int _mf = 0; _mf < 4; ++_mf) {                    \
            afr[_mf][0] = RDF(QM, PAR, wm * 64 + _mf * 16 + rl, gk);             \
            afr[_mf][1] = RDF(QM, PAR, wm * 64 + _mf * 16 + rl, 4 + gk);         \
        } }                                                                      \
    bf16x8 _b0 = RDF(2, PAR, (QN) * 64 + wn * 16 + rl, gk);                      \
    bf16x8 _b1 = RDF(2, PAR, (QN) * 64 + wn * 16 + rl, 4 + gk);                  \
    LWAIT; __builtin_amdgcn_sched_barrier(0);                                    \
    __builtin_amdgcn_s_setprio(1);                                               \
    _Pragma("unroll") for (int _mf = 0; _mf < 4; ++_mf) {                        \
        acc[QM][_mf][QN] = __builtin_amdgcn_mfma_f32_16x16x32_bf16(              \
            afr[_mf][0], _b0, acc[QM][_mf][QN], 0, 0, 0);                        \
        acc[QM][_mf][QN] = __builtin_amdgcn_mfma_f32_16x16x32_bf16(              \
            afr[_mf][1], _b1, acc[QM][_mf][QN], 0, 0, 0);                        \
    }                                                                            \
    __builtin_amdgcn_s_setprio(0);                                               \
    __builtin_amdgcn_s_barrier(); __builtin_amdgcn_sched_barrier(0);             \
} while (0)

    STAGE1(0, 0); STAGE1(1, 0); STAGE1(2, 0); STAGE1(0, 1);
    for (int i = 0; i < 8; ++i) {
        const int t = 2 * i;
        PHASE(0, 0, 0, 1, t + 1, 1);
        PHASE(0, 1, 0, 2, t + 1, 0);
        PHASE(1, 0, 0, 0, t + 2, 0);
        PHASE(1, 1, 0, -1, 0, 0);
        PHASE(0, 0, 1, 1, t + 2, (i == 7) ? 2 : 1);
        PHASE(0, 1, 1, 2, t + 2, 0);
        PHASE(1, 0, 1, 0, t + 3, 0);
        PHASE(1, 1, 1, -1, 0, 0);
    }
#undef PHASE
#undef RDF
#undef STAGE1
#pragma unroll
    for (int qm = 0; qm < 2; ++qm)
#pragma unroll
        for (int mf = 0; mf < 4; ++mf)
#pragma unroll
            for (int qn = 0; qn < 2; ++qn)
#pragma unroll
                for (int j = 0; j < 4; ++j) {
                    const int row = m0 + qm * 128 + wm * 64 + mf * 16 + r4 + j;
                    const int col = n0 + qn * 64 + wn * 16 + rl;
                    if (ISK4)
                        outf[(int64_t)row * 1024 + col] = acc[qm][mf][qn][j] + bias[col];
                    else
                        outh[(int64_t)row * 3072 + col] = f2bf(acc[qm][mf][qn][j]);
                }
}

// ---------------- K0v: pre-transpose V planes: Vt[z][e 128][kpos 1024]
__global__ __launch_bounds__(256, 2) void k0v_vt(const u16* __restrict__ Qh,
                                                 u16* __restrict__ Vt) {
    __shared__ u16 T[128][144];
    const int tid = threadIdx.x;
    const int z = blockIdx.y, b = z >> 4, h = z & 15;
    const int kt = blockIdx.x;
    const int c0v = (h < 8) ? (1024 + h * 128) : (2048 + (h - 8) * 128);
    const u16* Vbase = Qh + ((int64_t)b * 2048 + 1) * 3072 + c0v;
    const int row = tid >> 1, e0 = (tid & 1) << 6;
    const u16* src = Vbase + (int64_t)(kt * 128 + row) * 6144 + e0;
#pragma unroll
    for (int i = 0; i < 8; ++i) {
        us8 v = *reinterpret_cast<const us8*>(src + i * 8);
#pragma unroll
        for (int j = 0; j < 8; ++j) T[e0 + i * 8 + j][row] = v[j];
    }
    __syncthreads();
    const int e = tid >> 1, k0 = (tid & 1) << 6;
    u16* dst = Vt + ((int64_t)z << 17) + (int64_t)e * 1024 + kt * 128 + k0;
#pragma unroll
    for (int i = 0; i < 8; ++i)
        *reinterpret_cast<us8*>(dst + i * 8) = *reinterpret_cast<const us8*>(&T[e][k0 + i * 8]);
}

// ---------------- K23 v8 (R18 proven): QBLK=64, 512 thr (8 waves)
__global__ __launch_bounds__(512, 4) void k23_fused(const u16* __restrict__ Qh,
                                                    const u16* __restrict__ Vt,
                                                    float* __restrict__ attn,
                                                    u16* __restrict__ Obf) {
    __shared__ u16 LQ[8192];                         // 64x128
    __shared__ u16 LKV[3][8192];                     // 3 x (64x128 K | 128x64 V^T)
    __shared__ u16 Ph[64 * 72];                      // p~ bf16 [q][k] (+pad)
    __shared__ float pS[8][32];
    __shared__ float rowInv[64];
    const int tid = threadIdx.x, lane = tid & 63, w = tid >> 6;
    const u32 wgid = blockIdx.x;
    const int xcd = wgid & 7, t0 = wgid >> 3;        // T1: same-z -> same XCD
    const int mt = t0 & 15, z = ((t0 >> 4) << 3) + xcd;
    const int b = z >> 4, h = z & 15;
    const int m0 = mt << 6;                          // 64 q-rows per block
    const int kt = w & 3, qh = w >> 2;               // QK^T roles
    const int qq = w & 3, sv = w >> 2;               // PV roles
    const int rl = lane & 15, gk = lane >> 4, r4 = gk << 2;
    const u16* Qbase = Qh + ((int64_t)b * 2048 + 2 * m0) * 3072 + h * 128;
    const int pk  = (h < 8) ? 0 : 1;
    const int c0k = (h < 8) ? (2048 + h * 128) : ((h - 8) * 128);
    const u16* Kbase = Qh + ((int64_t)b * 2048 + pk) * 3072 + c0k;
    const u16* Vtz = Vt + ((int64_t)z << 17);
    float* attnZ = attn + ((int64_t)z << 20) + (int64_t)m0 * 1024;
    gld8_t64x128(Qbase, 6144, LQ, w, lane);          // Q 64x128 (2 ops)
    gld8_t64x128(Kbase,             6144, LKV[0], w, lane);
    gld8_t64x128(Kbase + 64 * 6144, 6144, LKV[1], w, lane);
    u32 pk0[32], pk1[32];
    float ssum0 = 0.f, ssum1 = 0.f;
#pragma unroll
    for (int t = 0; t < 16; ++t) {
        if (t == 15) { VWAIT(0); } else { VWAIT(2); }   // K(t) landed; K(t+1) in flight
        BARRIER;
        if (t < 14)
            gld8_t64x128(Kbase + (int64_t)(t + 2) * 64 * 6144, 6144, LKV[(t + 2) % 3], w, lane);
        f32x4 s0 = {}, s1 = {};
#pragma unroll
        for (int ks = 0; ks < 4; ++ks) {
            bf16x8 kf = *reinterpret_cast<const bf16x8*>(&LKV[t % 3][idxT(kt * 16 + rl, ks * 4 + gk)]);
            bf16x8 q0 = *reinterpret_cast<const bf16x8*>(&LQ[idxT(qh * 32 + rl, ks * 4 + gk)]);
            bf16x8 q1 = *reinterpret_cast<const bf16x8*>(&LQ[idxT(qh * 32 + 16 + rl, ks * 4 + gk)]);
            s0 = __builtin_amdgcn_mfma_f32_16x16x32_bf16(kf, q0, s0, 0, 0, 0);
            s1 = __builtin_amdgcn_mfma_f32_16x16x32_bf16(kf, q1, s1, 0, 0, 0);
        }
        float p0[4], p1[4];
#pragma unroll
        for (int j = 0; j < 4; ++j) {
            p0[j] = __expf(s0[j] * 0.125f); ssum0 += p0[j];
            p1[j] = __expf(s1[j] * 0.125f); ssum1 += p1[j];
        }
        pk0[2 * t]     = cvtpk(p0[0], p0[1]);
        pk1[2 * t]     = cvtpk(p0[2], p0[3]);
        pk0[2 * t + 1] = cvtpk(p1[0], p1[1]);
        pk1[2 * t + 1] = cvtpk(p1[2], p1[3]);
    }
    ssum0 += __shfl_xor(ssum0, 16); ssum0 += __shfl_xor(ssum0, 32);
    ssum1 += __shfl_xor(ssum1, 16); ssum1 += __shfl_xor(ssum1, 32);
    if (lane < 16) { pS[w][lane] = ssum0; pS[w][16 + lane] = ssum1; }
    LWAIT; BARRIER;                                  // all K readers done; buf0/1 free
    gld8_v128x64(Vtz,      1024, LKV[0], w, lane);   // V chunks 0,1 overlap stats
    gld8_v128x64(Vtz + 64, 1024, LKV[1], w, lane);
    if (tid < 64) {
        const int qb = (tid >> 5) << 2;              // q-half -> wave group base
        rowInv[tid] = 1.0f / (pS[qb][tid & 31] + pS[qb + 1][tid & 31]
                              + pS[qb + 2][tid & 31] + pS[qb + 3][tid & 31]);
    }
    LWAIT; BARRIER;
    const float Iq0 = rowInv[qh * 32 + rl], Iq1 = rowInv[qh * 32 + 16 + rl];
    float IqO[4];
#pragma unroll
    for (int j = 0; j < 4; ++j) IqO[j] = rowInv[qq * 16 + r4 + j];
    f32x4 po[4] = {};
#pragma unroll
    for (int t = 0; t < 16; ++t) {
        if (t == 0)       { VWAIT(2); }
        else if (t == 1)  { VWAIT(4); }
        else if (t == 15) { VWAIT(4); }
        else              { VWAIT(6); }
        BARRIER;
        if (t < 14)
            gld8_v128x64(Vtz + (t + 2) * 64, 1024, LKV[(t + 2) % 3], w, lane);
        const u32 a0 = pk0[2 * t], a1 = pk1[2 * t];
        const u32 b0 = pk0[2 * t + 1], b1 = pk1[2 * t + 1];
        *reinterpret_cast<uint2*>(&Ph[(qh * 32 + rl) * 72 + kt * 16 + r4])
            = make_uint2(a0, a1);
        *reinterpret_cast<uint2*>(&Ph[(qh * 32 + 16 + rl) * 72 + kt * 16 + r4])
            = make_uint2(b0, b1);
        *reinterpret_cast<float4*>(&attnZ[(int64_t)(qh * 32 + rl) * 1024 + t * 64 + kt * 16 + r4])
            = make_float4(__uint_as_float(a0 << 16) * Iq0,
                          __uint_as_float(a0 & 0xFFFF0000u) * Iq0,
                          __uint_as_float(a1 << 16) * Iq0,
                          __uint_as_float(a1 & 0xFFFF0000u) * Iq0);
        *reinterpret_cast<float4*>(&attnZ[(int64_t)(qh * 32 + 16 + rl) * 1024 + t * 64 + kt * 16 + r4])
            = make_float4(__uint_as_float(b0 << 16) * Iq1,
                          __uint_as_float(b0 & 0xFFFF0000u) * Iq1,
                          __uint_as_float(b1 << 16) * Iq1,
                          __uint_as_float(b1 & 0xFFFF0000u) * Iq1);
        LWAIT; BARRIER;                              // Ph visible (stores NOT drained)
        bf16x8 pa0 = *reinterpret_cast<const bf16x8*>(&Ph[(qq * 16 + rl) * 72 + gk * 8]);
        bf16x8 pa1 = *reinterpret_cast<const bf16x8*>(&Ph[(qq * 16 + rl) * 72 + 32 + gk * 8]);
#pragma unroll
        for (int n = 0; n < 4; ++n) {
            bf16x8 bv0 = *reinterpret_cast<const bf16x8*>(&LKV[t % 3][idxV(sv * 64 + n * 16 + rl, gk)]);
            bf16x8 bv1 = *reinterpret_cast<const bf16x8*>(&LKV[t % 3][idxV(sv * 64 + n * 16 + rl, 4 + gk)]);
            po[n] = __builtin_amdgcn_mfma_f32_16x16x32_bf16(pa0, bv0, po[n], 0, 0, 0);
            po[n] = __builtin_amdgcn_mfma_f32_16x16x32_bf16(pa1, bv1, po[n], 0, 0, 0);
        }
    }
    const int poh = h >> 3, cb2 = (h & 7) << 7;
#pragma unroll
    for (int n = 0; n < 4; ++n)
#pragma unroll
        for (int j = 0; j < 4; ++j) {
            const int qrow = m0 + qq * 16 + r4 + j;
            Obf[((int64_t)b * 2048 + 2 * qrow + poh) * 1024
                + cb2 + sv * 64 + n * 16 + rl] = f2bf(po[n][j] * IqO[j]);
        }
}

extern "C" void kernel_launch(void* const* d_in, const int* in_sizes, int n_in,
                              void* d_out, int out_size, void* d_ws, size_t ws_size,
                              hipStream_t stream) {
    const float* x     = (const float*)d_in[0];
    const float* ctx   = (const float*)d_in[1];
    const float* wqkv  = (const float*)d_in[2];
    const float* wproj = (const float*)d_in[3];
    const float* bias  = (const float*)d_in[4];
    float* out  = (float*)d_out;                 // [4,2048,1024]
    float* attn = out + 8388608;                 // [4,16,1024,1024] f32

    // ws (u16), total 92.3 MB
    u16* Qh  = (u16*)d_ws;                       // [8192,3072]
    u16* Vt  = Qh + 25165824;                    // [64,128,1024]
    u16* Wh  = Vt + 8388608;                     // [3072,1024]
    u16* Phw = Wh + 3145728;                     // [1024,1024]
    u16* Obf = Phw + 1048576;                    // [8192,1024]

    // X bf16 plane parked in the attn region (dead once k1 finishes)
    u16* Xh = (u16*)attn;                        // [8192,1024]

    k0_all            <<<dim3(6144), 256, 0, stream>>>(wqkv, x, ctx, wproj, Wh, Xh, Phw);
    gemm8p<false, 24> <<<dim3(768),  512, 0, stream>>>(Xh, Wh, nullptr, Qh, nullptr);
    k0v_vt            <<<dim3(8, 64), 256, 0, stream>>>(Qh, Vt);
    k23_fused         <<<dim3(1024), 512, 0, stream>>>(Qh, Vt, attn, Obf);
    gemm8p<true, 8>   <<<dim3(256),  512, 0, stream>>>(Obf, Phw, bias, nullptr, out);
}